// Round 18
// baseline (26.107 us; speedup 1.0000x reference)
//
#include <hip/hip_runtime.h>

// Gaussian-splat heatmap as a per-image MFMA GEMM — single pass, per-wave
// private bf16 staging, fire-and-forget contiguous drain, 2-image pipeline.
//   heat[y][x] = sum_p Rmat[y][p] * CmatT[x][p]   (M=N=200 padded to 224, K=64)
//   Rmat[y][p]  = k1n[y-ys_p] if 0<=y-ys_p<ky_p else 0  (top-left-slice quirk)
//   CmatT[x][p] = k1n[x-xs_p] if 0<=x-xs_p<kx_p else 0
// bf16 LDS rows of 128 B, XOR-swizzled byte ^= ((row&7)<<4) (G4/T2).
// mfma_f32_16x16x32_bf16 (verified R13/R16/R17): A row=lane&15, k=8*(lane>>4)+j
// (+32 second K-half); C/D col=lane&15 (=x), row=4*(lane>>4)+reg (=y).
//
// R17 postmortem: two lockstep blocks/CU serialize ~6us of prefix (build +
// pass1 + pass2 compute) before any store issues, then drain 320KB/CU. Fix:
// (a) SINGLE compute pass — stage unnormalized bf16 into per-wave private LDS
//     (both strips, 2x16 rows/wave), max-reduce, then drain with scale applied
//     during bf16->f32 conversion. Stores issue ~3us earlier.
// (b) two images per block (grid 256, 1 blk/CU, LDS 131KB): image-1's
//     LDS-only build+compute overlaps image-0's in-flight stores (fire-and-
//     forget; ~25 store instrs/wave << vmcnt cap, so issuance never stalls).
// Sequential single-buffer build (R17): build Rm -> cache A-frags -> rebuild
// same buffer as Cm. Drain spans are contiguous & 128B-aligned (full lines).
// Falsifier: >=23us -> plateau is structural (80MB + prefix at real write BW).

#define NT 64
#define TDIM 224
#define BLK 512

typedef short bf16x8 __attribute__((ext_vector_type(8)));
typedef float f32x4  __attribute__((ext_vector_type(4)));

// f32 -> bf16 round-to-nearest-even
static __device__ inline unsigned short f2bf(float f) {
    unsigned int u = __float_as_uint(f);
    u = (u + 0x7FFFu + ((u >> 16) & 1u)) >> 16;
    return (unsigned short)u;
}

struct __align__(16) SMem {
    unsigned short M[TDIM][64];          //  28,672 B: Rm, then rebuilt as Cm
    unsigned short stg[8][2][16][200];   // 102,400 B: per-wave, per-strip stage
    float k1f[37];
    float wmax[8];
};

__global__ __launch_bounds__(BLK) void heatmap_kernel(const float* __restrict__ x_t,
                                                      float* __restrict__ out) {
    __shared__ SMem s;
    const int tid  = threadIdx.x;
    const int lane = tid & 63;
    const int wv   = tid >> 6;          // 0..7
    const int swl  = (lane & 7) << 4;

    // --- normalized 1-D gaussian table (once, persists across both images) ---
    if (tid < 37) {
        float sum = 0.0f, mine = 0.0f;
        #pragma unroll
        for (int i = 0; i < 37; ++i) {
            float r = (float)(i - 18);
            float v = expf(-(r * r) * (1.0f / 18.0f));   // sigma=3 -> 2*sigma^2=18
            sum += v;
            if (i == tid) mine = v;
        }
        s.k1f[tid] = mine / sum;
    }

    const int s1 = wv, s2 = wv + 8;     // this wave's 16-row strips (s2 if < 13)

    for (int img = 0; img < 2; ++img) {
        const int b = 2 * blockIdx.x + img;

        // --- zero M (img0: also orders k1f; img1: all M reads done pre-max) ---
        __syncthreads();
        {
            uint4 z = {0u, 0u, 0u, 0u};
            uint4* base = (uint4*)s.M;
            #pragma unroll
            for (int i = 0; i < 4; ++i) {
                const int idx = tid + BLK * i;
                if (idx < 1792) base[idx] = z;
            }
        }
        __syncthreads();

        // --- per-point meta: 8 threads/point (replicates reference exactly) ---
        const int p = tid >> 3, j = tid & 7;
        const float2 xy = *(const float2*)(x_t + (size_t)b * 128 + 2 * p);
        const bool valid = (xy.x == xy.x) && (xy.y == xy.y);
        const int xp = (int)(xy.x * 2.0f);             // trunc == astype(int32), x>=0
        const int yp = 200 - (int)(xy.y * 2.0f);
        const int xs = min(max(xp - 18, 0), 164);
        const int ys = min(max(yp - 18, 0), 164);
        const int kx = valid ? (min(max(xp + 18, 0), 200) - xs) : 0;   // <= 36
        const int ky = valid ? (min(max(yp + 18, 0), 200) - ys) : 0;

        // --- build Rm (rows = y) ---
        #pragma unroll
        for (int i = 0; i < 5; ++i) {
            const int rel = j * 5 + i;                 // 0..39 covers 0..35
            if (rel < ky) {
                const int row = ys + rel;
                *(unsigned short*)((char*)s.M + row * 128 + ((2 * p) ^ ((row & 7) << 4)))
                    = f2bf(s.k1f[rel]);
            }
        }
        __syncthreads();

        // --- cache A-frags for both strips ---
        bf16x8 A10, A11, A20, A21;
        {
            const char* ab = (const char*)s.M + (16 * s1 + (lane & 15)) * 128;
            A10 = *(const bf16x8*)(ab + ((16 * (lane >> 4)) ^ swl));
            A11 = *(const bf16x8*)(ab + ((16 * (lane >> 4) + 64) ^ swl));
        }
        if (s2 < 13) {
            const char* ab = (const char*)s.M + (16 * s2 + (lane & 15)) * 128;
            A20 = *(const bf16x8*)(ab + ((16 * (lane >> 4)) ^ swl));
            A21 = *(const bf16x8*)(ab + ((16 * (lane >> 4) + 64) ^ swl));
        } else { A20 = A10; A21 = A11; }
        __syncthreads();                               // A-frag reads done

        // --- re-zero M, rebuild as Cm (rows = x) ---
        {
            uint4 z = {0u, 0u, 0u, 0u};
            uint4* base = (uint4*)s.M;
            #pragma unroll
            for (int i = 0; i < 4; ++i) {
                const int idx = tid + BLK * i;
                if (idx < 1792) base[idx] = z;
            }
        }
        __syncthreads();
        #pragma unroll
        for (int i = 0; i < 5; ++i) {
            const int rel = j * 5 + i;
            if (rel < kx) {
                const int row = xs + rel;
                *(unsigned short*)((char*)s.M + row * 128 + ((2 * p) ^ ((row & 7) << 4)))
                    = f2bf(s.k1f[rel]);
            }
        }
        __syncthreads();

        // --- single compute pass: strip -> unnormalized bf16 stage; f32 max ---
        float gmax = 0.0f;
        const int r0l = 4 * (lane >> 4), c0l = lane & 15;
        auto compute_stage = [&](int k, bf16x8 A0, bf16x8 A1) {
            f32x4 acc[13];
            #pragma unroll
            for (int t = 0; t < 13; ++t) {
                acc[t][0] = 0.0f; acc[t][1] = 0.0f; acc[t][2] = 0.0f; acc[t][3] = 0.0f;
            }
            #pragma unroll
            for (int t = 0; t < 13; ++t) {
                const char* bb = (const char*)s.M + (16 * t + (lane & 15)) * 128;
                bf16x8 B0 = *(const bf16x8*)(bb + ((16 * (lane >> 4)) ^ swl));
                bf16x8 B1 = *(const bf16x8*)(bb + ((16 * (lane >> 4) + 64) ^ swl));
                acc[t] = __builtin_amdgcn_mfma_f32_16x16x32_bf16(A0, B0, acc[t], 0, 0, 0);
                acc[t] = __builtin_amdgcn_mfma_f32_16x16x32_bf16(A1, B1, acc[t], 0, 0, 0);
            }
            unsigned short* st = &s.stg[wv][k][0][0];
            #pragma unroll
            for (int t = 0; t < 13; ++t) {
                const int col = 16 * t + c0l;
                #pragma unroll
                for (int r = 0; r < 4; ++r) gmax = fmaxf(gmax, acc[t][r]);
                if (col < 200) {                       // t=12 cols 200..207: skip
                    #pragma unroll
                    for (int r = 0; r < 4; ++r)
                        st[(r0l + r) * 200 + col] = f2bf(acc[t][r]);
                }
            }
        };
        compute_stage(0, A10, A11);
        if (s2 < 13) compute_stage(1, A20, A21);

        // --- block max reduce ---
        #pragma unroll
        for (int off = 32; off > 0; off >>= 1) gmax = fmaxf(gmax, __shfl_xor(gmax, off));
        if (lane == 0) s.wmax[wv] = gmax;
        __syncthreads();                               // also: all M reads done
        float mm = s.wmax[0];
        #pragma unroll
        for (int w = 1; w < 8; ++w) mm = fmaxf(mm, s.wmax[w]);
        const float scale = 1.0f / (mm + 1e-10f);

        // --- fire-and-forget drain: contiguous 128B-aligned full-line stores ---
        float* ob = out + (size_t)b * (200 * 200);
        auto drain = [&](int k, int ss) {
            const unsigned short* st = &s.stg[wv][k][0][0];
            const int nrow = min(16, 200 - 16 * ss);   // 16, or 8 for strip 12
            float* obs = ob + (size_t)(16 * ss) * 200;
            for (int i = lane; i < nrow * 50; i += 64) {
                uint2 v = *(const uint2*)(st + 4 * i);
                float4 o;
                o.x = __uint_as_float(v.x << 16) * scale;
                o.y = __uint_as_float(v.x & 0xFFFF0000u) * scale;
                o.z = __uint_as_float(v.y << 16) * scale;
                o.w = __uint_as_float(v.y & 0xFFFF0000u) * scale;
                *(float4*)(obs + 4 * i) = o;
            }
        };
        drain(0, s1);
        if (s2 < 13) drain(1, s2);
        // no barrier: stores stay in flight while the next image builds/computes
    }
}

extern "C" void kernel_launch(void* const* d_in, const int* in_sizes, int n_in,
                              void* d_out, int out_size, void* d_ws, size_t ws_size,
                              hipStream_t stream) {
    const float* x_t = (const float*)d_in[0];
    float* out = (float*)d_out;
    const int B = in_sizes[0] / (NT * 2);   // 512
    heatmap_kernel<<<B / 2, BLK, 0, stream>>>(x_t, out);
}